// Round 1
// baseline (3162.735 us; speedup 1.0000x reference)
//
#include <hip/hip_runtime.h>
#include <math.h>

#define HEAD_DIM 128
#define NHEADS   32
#define SLEN     8192
#define SPLITS   32
#define CHUNK    (SLEN / SPLITS)   /* 256 */
#define NLAYERS  32
#define PART_STRIDE (HEAD_DIM + 2) /* m, l, acc[128] */

// ---------------- copy K,V -> out ----------------
__global__ void copy_kv(const float4* __restrict__ k, const float4* __restrict__ v,
                        float4* __restrict__ out, size_t n4)
{
    size_t i = (size_t)blockIdx.x * blockDim.x + threadIdx.x;
    const size_t stride = (size_t)gridDim.x * blockDim.x;
    for (size_t j = i; j < n4; j += stride) {
        out[j]      = k[j];
        out[n4 + j] = v[j];
    }
}

// ---------------- per-(head, S-split) partial attention ----------------
__global__ __launch_bounds__(128)
void attn_partial(const float* __restrict__ x,   // [32,128]
                  const float* __restrict__ k,   // [32,8192,128]
                  const float* __restrict__ v,   // [32,8192,128]
                  float* __restrict__ part)      // [32, SPLITS, PART_STRIDE]
{
    const int h    = blockIdx.x / SPLITS;
    const int sp   = blockIdx.x % SPLITS;
    const int tid  = threadIdx.x;   // 0..127
    const int lane = tid & 63;
    const int wave = tid >> 6;      // 0..1

    __shared__ float xs[HEAD_DIM];
    __shared__ float sc[CHUNK];
    __shared__ float wred[2];

    xs[tid] = x[h * HEAD_DIM + tid];
    __syncthreads();

    const float scale = 0.088388347648318447f;  // 1/sqrt(128)
    const size_t base = ((size_t)h * SLEN + (size_t)sp * CHUNK) * HEAD_DIM;
    const float* __restrict__ kh = k + base;
    const float* __restrict__ vh = v + base;

    const float2 xv = *(const float2*)(xs + 2 * lane);

    // scores: each wave handles alternate s; lane owns 2 dims, 64-lane butterfly reduce
    for (int s = wave; s < CHUNK; s += 2) {
        const float2 kv = *(const float2*)(kh + (size_t)s * HEAD_DIM + 2 * lane);
        float p = kv.x * xv.x + kv.y * xv.y;
        #pragma unroll
        for (int off = 1; off < 64; off <<= 1)
            p += __shfl_xor(p, off);
        if (lane == 0) sc[s] = p * scale;
    }
    __syncthreads();

    // block max over CHUNK scores
    float lm = -3.0e38f;
    for (int s = tid; s < CHUNK; s += 128) lm = fmaxf(lm, sc[s]);
    #pragma unroll
    for (int off = 1; off < 64; off <<= 1)
        lm = fmaxf(lm, __shfl_xor(lm, off));
    if (lane == 0) wred[wave] = lm;
    __syncthreads();
    const float M = fmaxf(wred[0], wred[1]);
    __syncthreads();

    // exp + partial sum
    float ls = 0.f;
    for (int s = tid; s < CHUNK; s += 128) {
        const float e = __expf(sc[s] - M);
        sc[s] = e;
        ls += e;
    }
    #pragma unroll
    for (int off = 1; off < 64; off <<= 1)
        ls += __shfl_xor(ls, off);
    if (lane == 0) wred[wave] = ls;
    __syncthreads();
    const float L = wred[0] + wred[1];

    // PV: thread owns output dim `tid`; coalesced 512B row reads
    float acc = 0.f;
    #pragma unroll 8
    for (int s = 0; s < CHUNK; ++s)
        acc = fmaf(sc[s], vh[(size_t)s * HEAD_DIM + tid], acc);

    float* ph = part + ((size_t)h * SPLITS + sp) * PART_STRIDE;
    if (tid == 0) { ph[0] = M; ph[1] = L; }
    ph[2 + tid] = acc;
}

// ---------------- combine partials -> x_next ----------------
__global__ __launch_bounds__(128)
void attn_combine(const float* __restrict__ part, float* __restrict__ xout)
{
    const int h = blockIdx.x;   // 0..31
    const int d = threadIdx.x;  // 0..127
    const float* __restrict__ ph = part + (size_t)h * SPLITS * PART_STRIDE;

    float G = -3.0e38f;
    #pragma unroll
    for (int i = 0; i < SPLITS; ++i) G = fmaxf(G, ph[i * PART_STRIDE]);

    float L = 0.f, acc = 0.f;
    #pragma unroll
    for (int i = 0; i < SPLITS; ++i) {
        const float w = __expf(ph[i * PART_STRIDE] - G);
        L   = fmaf(ph[i * PART_STRIDE + 1], w, L);
        acc = fmaf(ph[i * PART_STRIDE + 2 + d], w, acc);
    }
    xout[h * HEAD_DIM + d] = acc / L;
}

extern "C" void kernel_launch(void* const* d_in, const int* in_sizes, int n_in,
                              void* d_out, int out_size, void* d_ws, size_t ws_size,
                              hipStream_t stream)
{
    const float* x = (const float*)d_in[0];  // [1,32,1,128]
    const float* k = (const float*)d_in[1];  // [1,32,8192,128]
    const float* v = (const float*)d_in[2];  // [1,32,8192,128]
    float* out = (float*)d_out;              // [k | v | x]

    const size_t kvN = (size_t)NHEADS * SLEN * HEAD_DIM;  // 33,554,432 floats

    // workspace layout: partials | x ping | x pong
    float* part = (float*)d_ws;
    float* xb0  = part + (size_t)NHEADS * SPLITS * PART_STRIDE;
    float* xb1  = xb0 + NHEADS * HEAD_DIM;

    // copy K, V to output (independent of the layer chain)
    copy_kv<<<2048, 256, 0, stream>>>((const float4*)k, (const float4*)v,
                                      (float4*)out, kvN / 4);

    const float* xin = x;
    for (int layer = 0; layer < NLAYERS; ++layer) {
        attn_partial<<<NHEADS * SPLITS, 128, 0, stream>>>(xin, k, v, part);
        float* xo = (layer == NLAYERS - 1) ? (out + 2 * kvN)
                                           : ((layer & 1) ? xb1 : xb0);
        attn_combine<<<NHEADS, 128, 0, stream>>>(part, xo);
        xin = xo;
    }
}

// Round 2
// 1526.475 us; speedup vs baseline: 2.0719x; 2.0719x over previous
//
#include <hip/hip_runtime.h>
#include <math.h>

#define HEAD_DIM 128
#define NHEADS   32
#define SLEN     8192
#define SPLITS   32
#define CHUNK    (SLEN / SPLITS)   /* 256 */
#define NLAYERS  32
#define PART_STRIDE (HEAD_DIM + 2) /* m, l, acc[128] */

// ---------------- copy K,V -> out ----------------
__global__ void copy_kv(const float4* __restrict__ k, const float4* __restrict__ v,
                        float4* __restrict__ out, size_t n4)
{
    size_t i = (size_t)blockIdx.x * blockDim.x + threadIdx.x;
    const size_t stride = (size_t)gridDim.x * blockDim.x;
    for (size_t j = i; j < n4; j += stride) {
        out[j]      = k[j];
        out[n4 + j] = v[j];
    }
}

// ---------------- per-(head, S-split) partial attention ----------------
__global__ __launch_bounds__(256)
void attn_partial(const float* __restrict__ x,   // [32,128]
                  const float* __restrict__ k,   // [32,8192,128]
                  const float* __restrict__ v,   // [32,8192,128]
                  float* __restrict__ part)      // [32, SPLITS, PART_STRIDE]
{
    const int h    = blockIdx.x / SPLITS;
    const int sp   = blockIdx.x % SPLITS;
    const int tid  = threadIdx.x;   // 0..255
    const int lane = tid & 63;
    const int wave = tid >> 6;      // 0..3

    __shared__ float xs[HEAD_DIM];
    __shared__ float pr[CHUNK];              // probs
    __shared__ float mred[4], lred[4];
    __shared__ float vred[8][HEAD_DIM];      // 4 KB PV partial sums

    if (tid < HEAD_DIM) xs[tid] = x[h * HEAD_DIM + tid];
    __syncthreads();

    const float scale = 0.088388347648318447f;  // 1/sqrt(128)
    const size_t base = ((size_t)h * SLEN + (size_t)sp * CHUNK) * HEAD_DIM;

    // ---- QK: lane owns one row; dot product fully in-lane ----
    const int r = wave * 64 + lane;            // 0..255
    const float* __restrict__ kr = k + base + (size_t)r * HEAD_DIM;
    float s = 0.f;
    #pragma unroll
    for (int d = 0; d < HEAD_DIM; d += 4) {
        const float4 kv = *(const float4*)(kr + d);
        const float4 xv = *(const float4*)(xs + d);
        s = fmaf(kv.x, xv.x, s);
        s = fmaf(kv.y, xv.y, s);
        s = fmaf(kv.z, xv.z, s);
        s = fmaf(kv.w, xv.w, s);
    }
    s *= scale;

    // ---- block max over 256 scores ----
    float m = s;
    #pragma unroll
    for (int off = 1; off < 64; off <<= 1)
        m = fmaxf(m, __shfl_xor(m, off));
    if (lane == 0) mred[wave] = m;
    __syncthreads();
    const float M = fmaxf(fmaxf(mred[0], mred[1]), fmaxf(mred[2], mred[3]));

    // ---- exp + block sum; stash probs in LDS ----
    const float p = __expf(s - M);
    pr[r] = p;
    float l = p;
    #pragma unroll
    for (int off = 1; off < 64; off <<= 1)
        l += __shfl_xor(l, off);
    if (lane == 0) lred[wave] = l;
    __syncthreads();                            // pr[] and lred[] visible
    const float L = lred[0] + lred[1] + lred[2] + lred[3];

    // ---- PV: thread owns 4 dims (float4), 8 row-groups ----
    const int d4   = (tid & 31) * 4;            // dim offset
    const int rg   = tid >> 5;                  // 0..7
    const float* __restrict__ vb = v + base;
    float4 acc = make_float4(0.f, 0.f, 0.f, 0.f);
    #pragma unroll 4
    for (int s0 = rg; s0 < CHUNK; s0 += 8) {
        const float4 vv = *(const float4*)(vb + (size_t)s0 * HEAD_DIM + d4);
        const float  pp = pr[s0];
        acc.x = fmaf(pp, vv.x, acc.x);
        acc.y = fmaf(pp, vv.y, acc.y);
        acc.z = fmaf(pp, vv.z, acc.z);
        acc.w = fmaf(pp, vv.w, acc.w);
    }
    *(float4*)(&vred[rg][d4]) = acc;
    __syncthreads();

    float* __restrict__ ph = part + ((size_t)h * SPLITS + sp) * PART_STRIDE;
    if (tid < HEAD_DIM) {
        float a = 0.f;
        #pragma unroll
        for (int g = 0; g < 8; ++g) a += vred[g][tid];
        ph[2 + tid] = a;
    }
    if (tid == 0) { ph[0] = M; ph[1] = L; }
}

// ---------------- combine partials -> x_next ----------------
__global__ __launch_bounds__(128)
void attn_combine(const float* __restrict__ part, float* __restrict__ xout)
{
    const int h = blockIdx.x;   // 0..31
    const int d = threadIdx.x;  // 0..127
    const float* __restrict__ ph = part + (size_t)h * SPLITS * PART_STRIDE;

    float G = -3.0e38f;
    #pragma unroll
    for (int i = 0; i < SPLITS; ++i) G = fmaxf(G, ph[i * PART_STRIDE]);

    float L = 0.f, acc = 0.f;
    #pragma unroll
    for (int i = 0; i < SPLITS; ++i) {
        const float w = __expf(ph[i * PART_STRIDE] - G);
        L   = fmaf(ph[i * PART_STRIDE + 1], w, L);
        acc = fmaf(ph[i * PART_STRIDE + 2 + d], w, acc);
    }
    xout[h * HEAD_DIM + d] = acc / L;
}

extern "C" void kernel_launch(void* const* d_in, const int* in_sizes, int n_in,
                              void* d_out, int out_size, void* d_ws, size_t ws_size,
                              hipStream_t stream)
{
    const float* x = (const float*)d_in[0];  // [1,32,1,128]
    const float* k = (const float*)d_in[1];  // [1,32,8192,128]
    const float* v = (const float*)d_in[2];  // [1,32,8192,128]
    float* out = (float*)d_out;              // [k | v | x]

    const size_t kvN = (size_t)NHEADS * SLEN * HEAD_DIM;  // 33,554,432 floats

    // workspace layout: partials | x ping | x pong
    float* part = (float*)d_ws;
    float* xb0  = part + (size_t)NHEADS * SPLITS * PART_STRIDE;
    float* xb1  = xb0 + NHEADS * HEAD_DIM;

    const float* xin = x;
    for (int layer = 0; layer < NLAYERS; ++layer) {
        attn_partial<<<NHEADS * SPLITS, 256, 0, stream>>>(xin, k, v, part);
        float* xo = (layer == NLAYERS - 1) ? (out + 2 * kvN)
                                           : ((layer & 1) ? xb1 : xb0);
        attn_combine<<<NHEADS, 128, 0, stream>>>(part, xo);
        xin = xo;
    }

    // copy K, V to output LAST so the layer loop keeps K+V resident in L3
    copy_kv<<<2048, 256, 0, stream>>>((const float4*)k, (const float4*)v,
                                      (float4*)out, kvN / 4);
}

// Round 3
// 918.227 us; speedup vs baseline: 3.4444x; 1.6624x over previous
//
#include <hip/hip_runtime.h>
#include <math.h>

#define HEAD_DIM 128
#define NHEADS   32
#define SLEN     8192
#define SPLITS   32
#define CHUNK    (SLEN / SPLITS)   /* 256 */
#define NLAYERS  32
#define PART_STRIDE (HEAD_DIM + 2) /* m, l, acc[128] */

typedef unsigned int  uint;
typedef unsigned short ushort;

__device__ __forceinline__ float bflo(uint u) { return __uint_as_float(u << 16); }
__device__ __forceinline__ float bfhi(uint u) { return __uint_as_float(u & 0xffff0000u); }
__device__ __forceinline__ uint pack2(float a, float b) {
    uint ua = __float_as_uint(a), ub = __float_as_uint(b);
    uint ra = (ua + 0x7fffu + ((ua >> 16) & 1u)) >> 16;   // RNE
    uint rb = (ub + 0x7fffu + ((ub >> 16) & 1u)) >> 16;
    return ra | (rb << 16);
}

// ---------------- convert K,V -> bf16 scratch (optionally also fp32 copy-out) ----
template<bool WRITE_OUT>
__global__ void convert_kv(const float4* __restrict__ k, const float4* __restrict__ v,
                           uint4* __restrict__ kb, uint4* __restrict__ vb,
                           float4* __restrict__ ok, float4* __restrict__ ov, size_t n8)
{
    size_t i = (size_t)blockIdx.x * blockDim.x + threadIdx.x;
    const size_t stride = (size_t)gridDim.x * blockDim.x;
    for (size_t j = i; j < n8; j += stride) {
        const float4 a0 = k[2 * j], a1 = k[2 * j + 1];
        uint4 kp;
        kp.x = pack2(a0.x, a0.y); kp.y = pack2(a0.z, a0.w);
        kp.z = pack2(a1.x, a1.y); kp.w = pack2(a1.z, a1.w);
        kb[j] = kp;
        const float4 b0 = v[2 * j], b1 = v[2 * j + 1];
        uint4 vp;
        vp.x = pack2(b0.x, b0.y); vp.y = pack2(b0.z, b0.w);
        vp.z = pack2(b1.x, b1.y); vp.w = pack2(b1.z, b1.w);
        vb[j] = vp;
        if (WRITE_OUT) {
            ok[2 * j] = a0; ok[2 * j + 1] = a1;
            ov[2 * j] = b0; ov[2 * j + 1] = b1;
        }
    }
}

// ---------------- copy K,V -> out (fallback path) ----------------
__global__ void copy_kv(const float4* __restrict__ k, const float4* __restrict__ v,
                        float4* __restrict__ out, size_t n4)
{
    size_t i = (size_t)blockIdx.x * blockDim.x + threadIdx.x;
    const size_t stride = (size_t)gridDim.x * blockDim.x;
    for (size_t j = i; j < n4; j += stride) {
        out[j]      = k[j];
        out[n4 + j] = v[j];
    }
}

// ---------------- fused layer: combine(prev partials) -> x, then split attention ----
__global__ __launch_bounds__(256)
void attn_layer(const float* __restrict__ x0,        // layer 0 input (else null)
                const float* __restrict__ part_in,   // prev partials (null on layer 0)
                const ushort* __restrict__ kb,       // bf16 K [32,8192,128]
                const ushort* __restrict__ vb,       // bf16 V
                float* __restrict__ part_out)        // [32, SPLITS, PART_STRIDE]
{
    const int h    = blockIdx.x / SPLITS;
    const int sp   = blockIdx.x % SPLITS;
    const int tid  = threadIdx.x;   // 0..255
    const int lane = tid & 63;
    const int wave = tid >> 6;

    __shared__ float xs[HEAD_DIM];
    __shared__ float pr[CHUNK];
    __shared__ float mred[4], lred[4];
    __shared__ float vred[16][HEAD_DIM];   // 8 KB

    // ---- prologue: produce x for this head ----
    if (part_in) {
        if (tid < HEAD_DIM) {
            const float* __restrict__ ph = part_in + (size_t)h * SPLITS * PART_STRIDE;
            float G = -3.0e38f;
            #pragma unroll
            for (int i = 0; i < SPLITS; ++i) G = fmaxf(G, ph[i * PART_STRIDE]);
            float L = 0.f, a = 0.f;
            #pragma unroll
            for (int i = 0; i < SPLITS; ++i) {
                const float w = __expf(ph[i * PART_STRIDE] - G);
                L = fmaf(ph[i * PART_STRIDE + 1], w, L);
                a = fmaf(ph[i * PART_STRIDE + 2 + tid], w, a);
            }
            xs[tid] = a / L;
        }
    } else {
        if (tid < HEAD_DIM) xs[tid] = x0[h * HEAD_DIM + tid];
    }
    __syncthreads();

    const size_t base = ((size_t)h * SLEN + (size_t)sp * CHUNK) * HEAD_DIM;

    // ---- QK: lane owns one row (bf16, 16B loads, decode via shift) ----
    const ushort* __restrict__ kr = kb + base + (size_t)tid * HEAD_DIM;
    float s = 0.f;
    #pragma unroll
    for (int d = 0; d < HEAD_DIM; d += 8) {
        const uint4 kv = *(const uint4*)(kr + d);
        s = fmaf(bflo(kv.x), xs[d + 0], s); s = fmaf(bfhi(kv.x), xs[d + 1], s);
        s = fmaf(bflo(kv.y), xs[d + 2], s); s = fmaf(bfhi(kv.y), xs[d + 3], s);
        s = fmaf(bflo(kv.z), xs[d + 4], s); s = fmaf(bfhi(kv.z), xs[d + 5], s);
        s = fmaf(bflo(kv.w), xs[d + 6], s); s = fmaf(bfhi(kv.w), xs[d + 7], s);
    }
    s *= 0.088388347648318447f;  // 1/sqrt(128)

    // ---- block max ----
    float m = s;
    #pragma unroll
    for (int off = 1; off < 64; off <<= 1)
        m = fmaxf(m, __shfl_xor(m, off));
    if (lane == 0) mred[wave] = m;
    __syncthreads();
    const float M = fmaxf(fmaxf(mred[0], mred[1]), fmaxf(mred[2], mred[3]));

    // ---- exp + block sum; probs to LDS ----
    const float p = __expf(s - M);
    pr[tid] = p;
    float l = p;
    #pragma unroll
    for (int off = 1; off < 64; off <<= 1)
        l += __shfl_xor(l, off);
    if (lane == 0) lred[wave] = l;
    __syncthreads();
    const float L = lred[0] + lred[1] + lred[2] + lred[3];

    // ---- PV: thread owns 8 dims (16B bf16 load), 16 row-groups ----
    const int rg = tid >> 4;          // 0..15
    const int d8 = (tid & 15) * 8;    // dim offset
    const ushort* __restrict__ vbase = vb + base;
    float acc[8] = {0.f, 0.f, 0.f, 0.f, 0.f, 0.f, 0.f, 0.f};
    #pragma unroll 4
    for (int s0 = rg; s0 < CHUNK; s0 += 16) {
        const uint4 vv = *(const uint4*)(vbase + (size_t)s0 * HEAD_DIM + d8);
        const float pp = pr[s0];
        acc[0] = fmaf(pp, bflo(vv.x), acc[0]); acc[1] = fmaf(pp, bfhi(vv.x), acc[1]);
        acc[2] = fmaf(pp, bflo(vv.y), acc[2]); acc[3] = fmaf(pp, bfhi(vv.y), acc[3]);
        acc[4] = fmaf(pp, bflo(vv.z), acc[4]); acc[5] = fmaf(pp, bfhi(vv.z), acc[5]);
        acc[6] = fmaf(pp, bflo(vv.w), acc[6]); acc[7] = fmaf(pp, bfhi(vv.w), acc[7]);
    }
    *(float4*)&vred[rg][d8]     = make_float4(acc[0], acc[1], acc[2], acc[3]);
    *(float4*)&vred[rg][d8 + 4] = make_float4(acc[4], acc[5], acc[6], acc[7]);
    __syncthreads();

    float* __restrict__ ph = part_out + ((size_t)h * SPLITS + sp) * PART_STRIDE;
    if (tid < HEAD_DIM) {
        float a = 0.f;
        #pragma unroll
        for (int g = 0; g < 16; ++g) a += vred[g][tid];
        ph[2 + tid] = a;
    }
    if (tid == 0) { ph[0] = M; ph[1] = L; }
}

// ---------------- final combine -> x out ----------------
__global__ __launch_bounds__(128)
void attn_combine(const float* __restrict__ part, float* __restrict__ xout)
{
    const int h = blockIdx.x;
    const int d = threadIdx.x;
    const float* __restrict__ ph = part + (size_t)h * SPLITS * PART_STRIDE;

    float G = -3.0e38f;
    #pragma unroll
    for (int i = 0; i < SPLITS; ++i) G = fmaxf(G, ph[i * PART_STRIDE]);

    float L = 0.f, acc = 0.f;
    #pragma unroll
    for (int i = 0; i < SPLITS; ++i) {
        const float w = __expf(ph[i * PART_STRIDE] - G);
        L   = fmaf(ph[i * PART_STRIDE + 1], w, L);
        acc = fmaf(ph[i * PART_STRIDE + 2 + d], w, acc);
    }
    xout[h * HEAD_DIM + d] = acc / L;
}

extern "C" void kernel_launch(void* const* d_in, const int* in_sizes, int n_in,
                              void* d_out, int out_size, void* d_ws, size_t ws_size,
                              hipStream_t stream)
{
    const float* x = (const float*)d_in[0];
    const float* k = (const float*)d_in[1];
    const float* v = (const float*)d_in[2];
    float* out = (float*)d_out;

    const size_t kvN = (size_t)NHEADS * SLEN * HEAD_DIM;       // 33,554,432
    const size_t partElems = (size_t)NHEADS * SPLITS * PART_STRIDE;

    float* part0 = (float*)d_ws;
    float* part1 = part0 + partElems;

    // bf16 scratch: prefer workspace; fall back to the d_out K/V region
    const size_t needWs = 2 * partElems * sizeof(float) + kvN * 2 * sizeof(ushort);
    ushort* kb;
    ushort* vb;
    const bool ws_path = (ws_size >= needWs + 256);
    if (ws_path) {
        kb = (ushort*)(part0 + 2 * partElems);
    } else {
        kb = (ushort*)out;          // temporary; overwritten by copy_kv at end
    }
    vb = kb + kvN;

    if (ws_path) {
        // fused: bf16 scratch + fp32 K/V copy-out in one pass
        convert_kv<true><<<2048, 256, 0, stream>>>(
            (const float4*)k, (const float4*)v, (uint4*)kb, (uint4*)vb,
            (float4*)out, (float4*)(out + kvN), kvN / 8);
    } else {
        convert_kv<false><<<2048, 256, 0, stream>>>(
            (const float4*)k, (const float4*)v, (uint4*)kb, (uint4*)vb,
            nullptr, nullptr, kvN / 8);
    }

    for (int layer = 0; layer < NLAYERS; ++layer) {
        float* pout = (layer & 1) ? part1 : part0;
        const float* pin = (layer == 0) ? nullptr : ((layer & 1) ? part0 : part1);
        attn_layer<<<NHEADS * SPLITS, 256, 0, stream>>>(
            (layer == 0) ? x : nullptr, pin, kb, vb, pout);
    }
    attn_combine<<<NHEADS, 128, 0, stream>>>(part1, out + 2 * kvN);  // layer 31 -> part1

    if (!ws_path) {
        copy_kv<<<2048, 256, 0, stream>>>((const float4*)k, (const float4*)v,
                                          (float4*)out, kvN / 4);
    }
}

// Round 4
// 859.408 us; speedup vs baseline: 3.6801x; 1.0684x over previous
//
#include <hip/hip_runtime.h>
#include <math.h>

#define HEAD_DIM 128
#define NHEADS   32
#define SLEN     8192
#define SPLITS   32
#define CHUNK    (SLEN / SPLITS)   /* 256 */
#define NLAYERS  32
#define PART_STRIDE (HEAD_DIM + 2) /* m, l, acc[128] */

typedef unsigned int  uint;
typedef unsigned short ushort;

__device__ __forceinline__ float bflo(uint u) { return __uint_as_float(u << 16); }
__device__ __forceinline__ float bfhi(uint u) { return __uint_as_float(u & 0xffff0000u); }
__device__ __forceinline__ uint pack2(float a, float b) {
    uint ua = __float_as_uint(a), ub = __float_as_uint(b);
    uint ra = (ua + 0x7fffu + ((ua >> 16) & 1u)) >> 16;   // RNE
    uint rb = (ub + 0x7fffu + ((ub >> 16) & 1u)) >> 16;
    return ra | (rb << 16);
}

// ---- K: fp32 [h][s][d] -> bf16 TRANSPOSED [h][d][s] (+ optional fp32 copy-out) ----
template<bool WRITE_OUT>
__global__ __launch_bounds__(256)
void convert_kT(const float* __restrict__ k, ushort* __restrict__ kbt,
                float* __restrict__ kout)
{
    const int h   = blockIdx.x >> 7;      // 128 s-tiles of 64 per head
    const int st  = blockIdx.x & 127;
    const int tid = threadIdx.x;

    __shared__ float tile[HEAD_DIM][65];  // [d][s_local], padded

    const int   srow0 = tid >> 5;         // 0..7
    const int   c4    = (tid & 31) * 4;   // 0..124
    const size_t kbase = ((size_t)h * SLEN + (size_t)st * 64) * HEAD_DIM;

    #pragma unroll
    for (int it = 0; it < 8; ++it) {
        const int s = srow0 + it * 8;
        const float4 v = *(const float4*)(k + kbase + (size_t)s * HEAD_DIM + c4);
        if (WRITE_OUT) *(float4*)(kout + kbase + (size_t)s * HEAD_DIM + c4) = v;
        tile[c4 + 0][s] = v.x; tile[c4 + 1][s] = v.y;
        tile[c4 + 2][s] = v.z; tile[c4 + 3][s] = v.w;
    }
    __syncthreads();

    const int d0 = tid >> 4;              // 0..15
    const int sl = (tid & 15) * 4;        // 0..60
    #pragma unroll
    for (int it = 0; it < 8; ++it) {
        const int d = d0 + it * 16;
        uint2 u;
        u.x = pack2(tile[d][sl + 0], tile[d][sl + 1]);
        u.y = pack2(tile[d][sl + 2], tile[d][sl + 3]);
        *(uint2*)(kbt + ((size_t)h * HEAD_DIM + d) * SLEN + st * 64 + sl) = u;
    }
}

// ---- V: fp32 -> bf16 row-major (+ optional fp32 copy-out) ----
template<bool WRITE_OUT>
__global__ void convert_v(const float4* __restrict__ v, uint4* __restrict__ vb,
                          float4* __restrict__ vout, size_t n8)
{
    size_t i = (size_t)blockIdx.x * blockDim.x + threadIdx.x;
    const size_t stride = (size_t)gridDim.x * blockDim.x;
    for (size_t j = i; j < n8; j += stride) {
        const float4 b0 = v[2 * j], b1 = v[2 * j + 1];
        uint4 vp;
        vp.x = pack2(b0.x, b0.y); vp.y = pack2(b0.z, b0.w);
        vp.z = pack2(b1.x, b1.y); vp.w = pack2(b1.z, b1.w);
        vb[j] = vp;
        if (WRITE_OUT) { vout[2 * j] = b0; vout[2 * j + 1] = b1; }
    }
}

// ---- fallback copy ----
__global__ void copy_kv(const float4* __restrict__ k, const float4* __restrict__ v,
                        float4* __restrict__ out, size_t n4)
{
    size_t i = (size_t)blockIdx.x * blockDim.x + threadIdx.x;
    const size_t stride = (size_t)gridDim.x * blockDim.x;
    for (size_t j = i; j < n4; j += stride) {
        out[j]      = k[j];
        out[n4 + j] = v[j];
    }
}

// ---- fused layer: combine(prev partials) -> x, then split attention ----
__global__ __launch_bounds__(256)
void attn_layer(const float* __restrict__ x0,
                const float* __restrict__ part_in,
                const ushort* __restrict__ kbt,  // bf16 K^T [32,128,8192]
                const ushort* __restrict__ vb,   // bf16 V   [32,8192,128]
                float* __restrict__ part_out)
{
    const int h    = blockIdx.x >> 5;
    const int sp   = blockIdx.x & 31;
    const int tid  = threadIdx.x;   // 0..255
    const int lane = tid & 63;
    const int w    = tid >> 6;

    __shared__ float xs[HEAD_DIM];
    __shared__ float scp[4][CHUNK];        // 4 KB: per-wave score partials
    __shared__ float pr[CHUNK];
    __shared__ float mred[4], lred[4];
    __shared__ float vred[16][HEAD_DIM];   // 8 KB

    // ---- prologue: produce x for this head ----
    if (part_in) {
        if (tid < HEAD_DIM) {
            const float* __restrict__ ph = part_in + (size_t)h * SPLITS * PART_STRIDE;
            float G = -3.0e38f;
            #pragma unroll
            for (int i = 0; i < SPLITS; ++i) G = fmaxf(G, ph[i * PART_STRIDE]);
            float L = 0.f, a = 0.f;
            #pragma unroll
            for (int i = 0; i < SPLITS; ++i) {
                const float wv = __expf(ph[i * PART_STRIDE] - G);
                L = fmaf(ph[i * PART_STRIDE + 1], wv, L);
                a = fmaf(ph[i * PART_STRIDE + 2 + tid], wv, a);
            }
            xs[tid] = a / L;
        }
    } else {
        if (tid < HEAD_DIM) xs[tid] = x0[h * HEAD_DIM + tid];
    }
    __syncthreads();

    // ---- QK from K^T: lane owns 8 consecutive s-columns; coalesced 1KB/instr ----
    const int sq   = (lane & 31) * 8;     // s offset within chunk
    const int dpar = lane >> 5;           // d parity within wave
    const ushort* __restrict__ kh = kbt + (size_t)h * HEAD_DIM * SLEN + (size_t)sp * CHUNK;
    float a8[8] = {0.f, 0.f, 0.f, 0.f, 0.f, 0.f, 0.f, 0.f};
    #pragma unroll
    for (int it = 0; it < 16; ++it) {
        const int d = w * 2 + dpar + it * 8;
        const uint4 kk = *(const uint4*)(kh + (size_t)d * SLEN + sq);
        const float xd = xs[d];
        a8[0] = fmaf(bflo(kk.x), xd, a8[0]); a8[1] = fmaf(bfhi(kk.x), xd, a8[1]);
        a8[2] = fmaf(bflo(kk.y), xd, a8[2]); a8[3] = fmaf(bfhi(kk.y), xd, a8[3]);
        a8[4] = fmaf(bflo(kk.z), xd, a8[4]); a8[5] = fmaf(bfhi(kk.z), xd, a8[5]);
        a8[6] = fmaf(bflo(kk.w), xd, a8[6]); a8[7] = fmaf(bfhi(kk.w), xd, a8[7]);
    }
    #pragma unroll
    for (int j = 0; j < 8; ++j) a8[j] += __shfl_xor(a8[j], 32);
    if (lane < 32) {
        *(float4*)&scp[w][sq]     = make_float4(a8[0], a8[1], a8[2], a8[3]);
        *(float4*)&scp[w][sq + 4] = make_float4(a8[4], a8[5], a8[6], a8[7]);
    }
    __syncthreads();

    const float s = (scp[0][tid] + scp[1][tid] + scp[2][tid] + scp[3][tid])
                    * 0.088388347648318447f;  // 1/sqrt(128)

    // ---- block max ----
    float m = s;
    #pragma unroll
    for (int off = 1; off < 64; off <<= 1)
        m = fmaxf(m, __shfl_xor(m, off));
    if (lane == 0) mred[w] = m;
    __syncthreads();
    const float M = fmaxf(fmaxf(mred[0], mred[1]), fmaxf(mred[2], mred[3]));

    // ---- exp + block sum; probs to LDS ----
    const float p = __expf(s - M);
    pr[tid] = p;
    float l = p;
    #pragma unroll
    for (int off = 1; off < 64; off <<= 1)
        l += __shfl_xor(l, off);
    if (lane == 0) lred[w] = l;
    __syncthreads();
    const float L = lred[0] + lred[1] + lred[2] + lred[3];

    // ---- PV: thread owns 8 dims (16B bf16 load), 16 row-groups ----
    const int rg = tid >> 4;          // 0..15
    const int d8 = (tid & 15) * 8;
    const ushort* __restrict__ vbase = vb + ((size_t)h * SLEN + (size_t)sp * CHUNK) * HEAD_DIM;
    float acc[8] = {0.f, 0.f, 0.f, 0.f, 0.f, 0.f, 0.f, 0.f};
    #pragma unroll 4
    for (int s0 = rg; s0 < CHUNK; s0 += 16) {
        const uint4 vv = *(const uint4*)(vbase + (size_t)s0 * HEAD_DIM + d8);
        const float pp = pr[s0];
        acc[0] = fmaf(pp, bflo(vv.x), acc[0]); acc[1] = fmaf(pp, bfhi(vv.x), acc[1]);
        acc[2] = fmaf(pp, bflo(vv.y), acc[2]); acc[3] = fmaf(pp, bfhi(vv.y), acc[3]);
        acc[4] = fmaf(pp, bflo(vv.z), acc[4]); acc[5] = fmaf(pp, bfhi(vv.z), acc[5]);
        acc[6] = fmaf(pp, bflo(vv.w), acc[6]); acc[7] = fmaf(pp, bfhi(vv.w), acc[7]);
    }
    *(float4*)&vred[rg][d8]     = make_float4(acc[0], acc[1], acc[2], acc[3]);
    *(float4*)&vred[rg][d8 + 4] = make_float4(acc[4], acc[5], acc[6], acc[7]);
    __syncthreads();

    float* __restrict__ ph = part_out + ((size_t)h * SPLITS + sp) * PART_STRIDE;
    if (tid < HEAD_DIM) {
        float a = 0.f;
        #pragma unroll
        for (int g = 0; g < 16; ++g) a += vred[g][tid];
        ph[2 + tid] = a;
    }
    if (tid == 0) { ph[0] = M; ph[1] = L; }
}

// ---- final combine -> x out ----
__global__ __launch_bounds__(128)
void attn_combine(const float* __restrict__ part, float* __restrict__ xout)
{
    const int h = blockIdx.x;
    const int d = threadIdx.x;
    const float* __restrict__ ph = part + (size_t)h * SPLITS * PART_STRIDE;

    float G = -3.0e38f;
    #pragma unroll
    for (int i = 0; i < SPLITS; ++i) G = fmaxf(G, ph[i * PART_STRIDE]);

    float L = 0.f, acc = 0.f;
    #pragma unroll
    for (int i = 0; i < SPLITS; ++i) {
        const float w = __expf(ph[i * PART_STRIDE] - G);
        L   = fmaf(ph[i * PART_STRIDE + 1], w, L);
        acc = fmaf(ph[i * PART_STRIDE + 2 + d], w, acc);
    }
    xout[h * HEAD_DIM + d] = acc / L;
}

extern "C" void kernel_launch(void* const* d_in, const int* in_sizes, int n_in,
                              void* d_out, int out_size, void* d_ws, size_t ws_size,
                              hipStream_t stream)
{
    const float* x = (const float*)d_in[0];
    const float* k = (const float*)d_in[1];
    const float* v = (const float*)d_in[2];
    float* out = (float*)d_out;

    const size_t kvN = (size_t)NHEADS * SLEN * HEAD_DIM;       // 33,554,432
    const size_t partElems = (size_t)NHEADS * SPLITS * PART_STRIDE;

    float* part0 = (float*)d_ws;
    float* part1 = part0 + partElems;

    const size_t needWs = 2 * partElems * sizeof(float) + kvN * 2 * sizeof(ushort);
    ushort* kbt;
    ushort* vb;
    const bool ws_path = (ws_size >= needWs + 256);
    if (ws_path) kbt = (ushort*)(part0 + 2 * partElems);
    else         kbt = (ushort*)out;   // temp scratch in out K/V region; copy_kv at end
    vb = kbt + kvN;

    if (ws_path) {
        convert_kT<true><<<NHEADS * 128, 256, 0, stream>>>(k, kbt, out);
        convert_v<true><<<2048, 256, 0, stream>>>(
            (const float4*)v, (uint4*)vb, (float4*)(out + kvN), kvN / 8);
    } else {
        convert_kT<false><<<NHEADS * 128, 256, 0, stream>>>(k, kbt, nullptr);
        convert_v<false><<<2048, 256, 0, stream>>>(
            (const float4*)v, (uint4*)vb, nullptr, kvN / 8);
    }

    for (int layer = 0; layer < NLAYERS; ++layer) {
        float* pout = (layer & 1) ? part1 : part0;
        const float* pin = (layer == 0) ? nullptr : ((layer & 1) ? part0 : part1);
        attn_layer<<<NHEADS * SPLITS, 256, 0, stream>>>(
            (layer == 0) ? x : nullptr, pin, kbt, vb, pout);
    }
    attn_combine<<<NHEADS, 128, 0, stream>>>(part1, out + 2 * kvN);  // layer 31 -> part1

    if (!ws_path) {
        copy_kv<<<2048, 256, 0, stream>>>((const float4*)k, (const float4*)v,
                                          (float4*)out, kvN / 4);
    }
}

// Round 5
// 639.011 us; speedup vs baseline: 4.9494x; 1.3449x over previous
//
#include <hip/hip_runtime.h>
#include <math.h>

#define HEAD_DIM 128
#define NHEADS   32
#define SLEN     8192
#define SPLITS   32
#define CHUNK    (SLEN / SPLITS)   /* 256 */
#define NLAYERS  32
#define PART_STRIDE (HEAD_DIM + 2) /* m, l, acc[128] */

typedef unsigned int   uint;
typedef unsigned short ushort;
typedef unsigned char  uchar;
typedef __attribute__((ext_vector_type(2))) float f2v;

// ---- fp8 e4m3 hardware converters (gfx950 OCP) ----
__device__ __forceinline__ f2v dec_lo(uint w) { return __builtin_amdgcn_cvt_pk_f32_fp8((int)w, false); }
__device__ __forceinline__ f2v dec_hi(uint w) { return __builtin_amdgcn_cvt_pk_f32_fp8((int)w, true);  }
__device__ __forceinline__ uint pk4(float a, float b, float c, float d) {
    int r = __builtin_amdgcn_cvt_pk_fp8_f32(a, b, 0, false);
    r     = __builtin_amdgcn_cvt_pk_fp8_f32(c, d, r, true);
    return (uint)r;
}

// ---- K: fp32 [h][s][d] -> fp8 TRANSPOSED [h][d][s] (+ optional fp32 copy-out) ----
template<bool WRITE_OUT>
__global__ __launch_bounds__(256)
void convert_kT(const float* __restrict__ k, uchar* __restrict__ kbt,
                float* __restrict__ kout)
{
    const int h   = blockIdx.x >> 7;      // 128 s-tiles of 64 per head
    const int st  = blockIdx.x & 127;
    const int tid = threadIdx.x;

    __shared__ float tile[HEAD_DIM][65];  // [d][s_local], padded

    const int   srow0 = tid >> 5;         // 0..7
    const int   c4    = (tid & 31) * 4;   // 0..124
    const size_t kbase = ((size_t)h * SLEN + (size_t)st * 64) * HEAD_DIM;

    #pragma unroll
    for (int it = 0; it < 8; ++it) {
        const int s = srow0 + it * 8;
        const float4 v = *(const float4*)(k + kbase + (size_t)s * HEAD_DIM + c4);
        if (WRITE_OUT) *(float4*)(kout + kbase + (size_t)s * HEAD_DIM + c4) = v;
        tile[c4 + 0][s] = v.x; tile[c4 + 1][s] = v.y;
        tile[c4 + 2][s] = v.z; tile[c4 + 3][s] = v.w;
    }
    __syncthreads();

    const int d0 = tid >> 3;              // 0..31
    const int sl = (tid & 7) * 8;         // 0..56
    #pragma unroll
    for (int it = 0; it < 4; ++it) {
        const int d = d0 + it * 32;
        uint2 u;
        u.x = pk4(tile[d][sl + 0], tile[d][sl + 1], tile[d][sl + 2], tile[d][sl + 3]);
        u.y = pk4(tile[d][sl + 4], tile[d][sl + 5], tile[d][sl + 6], tile[d][sl + 7]);
        *(uint2*)(kbt + ((size_t)h * HEAD_DIM + d) * SLEN + st * 64 + sl) = u;
    }
}

// ---- V: fp32 -> fp8 row-major (+ optional fp32 copy-out) ----
template<bool WRITE_OUT>
__global__ void convert_v(const float4* __restrict__ v, uint4* __restrict__ vb,
                          float4* __restrict__ vout, size_t n16)
{
    size_t i = (size_t)blockIdx.x * blockDim.x + threadIdx.x;
    const size_t stride = (size_t)gridDim.x * blockDim.x;
    for (size_t j = i; j < n16; j += stride) {
        const float4 b0 = v[4 * j], b1 = v[4 * j + 1], b2 = v[4 * j + 2], b3 = v[4 * j + 3];
        if (WRITE_OUT) {
            vout[4 * j] = b0; vout[4 * j + 1] = b1;
            vout[4 * j + 2] = b2; vout[4 * j + 3] = b3;
        }
        uint4 p;
        p.x = pk4(b0.x, b0.y, b0.z, b0.w);
        p.y = pk4(b1.x, b1.y, b1.z, b1.w);
        p.z = pk4(b2.x, b2.y, b2.z, b2.w);
        p.w = pk4(b3.x, b3.y, b3.z, b3.w);
        vb[j] = p;
    }
}

// ---- fallback copy ----
__global__ void copy_kv(const float4* __restrict__ k, const float4* __restrict__ v,
                        float4* __restrict__ out, size_t n4)
{
    size_t i = (size_t)blockIdx.x * blockDim.x + threadIdx.x;
    const size_t stride = (size_t)gridDim.x * blockDim.x;
    for (size_t j = i; j < n4; j += stride) {
        out[j]      = k[j];
        out[n4 + j] = v[j];
    }
}

// ---- fused layer: combine(prev partials) -> x, then split attention ----
__global__ __launch_bounds__(256)
void attn_layer(const float* __restrict__ x0,
                const float* __restrict__ part_in,
                const uchar* __restrict__ kbt,   // fp8 K^T [32,128,8192]
                const uchar* __restrict__ vb,    // fp8 V   [32,8192,128]
                float* __restrict__ part_out)
{
    const int h    = blockIdx.x >> 5;
    const int sp   = blockIdx.x & 31;
    const int tid  = threadIdx.x;   // 0..255
    const int lane = tid & 63;
    const int w    = tid >> 6;

    __shared__ float xs[HEAD_DIM];
    __shared__ float scp[4][CHUNK];        // 4 KB
    __shared__ float pr[CHUNK];
    __shared__ float mred[4], lred[4];
    __shared__ float vred[32][HEAD_DIM];   // 16 KB

    // ---- prologue: produce x for this head ----
    if (part_in) {
        if (tid < HEAD_DIM) {
            const float* __restrict__ ph = part_in + (size_t)h * SPLITS * PART_STRIDE;
            float G = -3.0e38f;
            #pragma unroll
            for (int i = 0; i < SPLITS; ++i) G = fmaxf(G, ph[i * PART_STRIDE]);
            float L = 0.f, a = 0.f;
            #pragma unroll
            for (int i = 0; i < SPLITS; ++i) {
                const float wv = __expf(ph[i * PART_STRIDE] - G);
                L = fmaf(ph[i * PART_STRIDE + 1], wv, L);
                a = fmaf(ph[i * PART_STRIDE + 2 + tid], wv, a);
            }
            xs[tid] = a / L;
        }
    } else {
        if (tid < HEAD_DIM) xs[tid] = x0[h * HEAD_DIM + tid];
    }
    __syncthreads();

    // ---- QK from fp8 K^T: lane owns 16 consecutive s; 4x256B segments/instr ----
    const int sgrp = lane & 15;
    const int s0   = sgrp * 16;
    const int dgrp = lane >> 4;           // 0..3
    const uchar* __restrict__ kh = kbt + (size_t)h * HEAD_DIM * SLEN + (size_t)sp * CHUNK;
    float a16[16];
    #pragma unroll
    for (int j = 0; j < 16; ++j) a16[j] = 0.f;
    #pragma unroll
    for (int it = 0; it < 8; ++it) {
        const int d = it * 16 + (w << 2) + dgrp;
        const uint4 kk = *(const uint4*)(kh + (size_t)d * SLEN + s0);
        const float xd = xs[d];
        f2v t;
        t = dec_lo(kk.x); a16[0]  = fmaf(t.x, xd, a16[0]);  a16[1]  = fmaf(t.y, xd, a16[1]);
        t = dec_hi(kk.x); a16[2]  = fmaf(t.x, xd, a16[2]);  a16[3]  = fmaf(t.y, xd, a16[3]);
        t = dec_lo(kk.y); a16[4]  = fmaf(t.x, xd, a16[4]);  a16[5]  = fmaf(t.y, xd, a16[5]);
        t = dec_hi(kk.y); a16[6]  = fmaf(t.x, xd, a16[6]);  a16[7]  = fmaf(t.y, xd, a16[7]);
        t = dec_lo(kk.z); a16[8]  = fmaf(t.x, xd, a16[8]);  a16[9]  = fmaf(t.y, xd, a16[9]);
        t = dec_hi(kk.z); a16[10] = fmaf(t.x, xd, a16[10]); a16[11] = fmaf(t.y, xd, a16[11]);
        t = dec_lo(kk.w); a16[12] = fmaf(t.x, xd, a16[12]); a16[13] = fmaf(t.y, xd, a16[13]);
        t = dec_hi(kk.w); a16[14] = fmaf(t.x, xd, a16[14]); a16[15] = fmaf(t.y, xd, a16[15]);
    }
    #pragma unroll
    for (int j = 0; j < 16; ++j) {
        a16[j] += __shfl_xor(a16[j], 16);
        a16[j] += __shfl_xor(a16[j], 32);
    }
    if (lane < 16) {
        #pragma unroll
        for (int j = 0; j < 16; j += 4)
            *(float4*)&scp[w][s0 + j] = make_float4(a16[j], a16[j+1], a16[j+2], a16[j+3]);
    }
    __syncthreads();

    const float s = (scp[0][tid] + scp[1][tid] + scp[2][tid] + scp[3][tid])
                    * 0.088388347648318447f;  // 1/sqrt(128)

    // ---- block max ----
    float m = s;
    #pragma unroll
    for (int off = 1; off < 64; off <<= 1)
        m = fmaxf(m, __shfl_xor(m, off));
    if (lane == 0) mred[w] = m;
    __syncthreads();
    const float M = fmaxf(fmaxf(mred[0], mred[1]), fmaxf(mred[2], mred[3]));

    // ---- exp + block sum; probs to LDS ----
    const float p = __expf(s - M);
    pr[tid] = p;
    float l = p;
    #pragma unroll
    for (int off = 1; off < 64; off <<= 1)
        l += __shfl_xor(l, off);
    if (lane == 0) lred[w] = l;
    __syncthreads();
    const float L = lred[0] + lred[1] + lred[2] + lred[3];

    // ---- PV: thread owns 16 dims (uint4 fp8), 32 row-groups; 1KB contiguous/instr ----
    const int rg  = tid >> 3;          // 0..31
    const int d16 = (tid & 7) * 16;    // 0..112
    const uchar* __restrict__ vbase = vb + ((size_t)h * SLEN + (size_t)sp * CHUNK) * HEAD_DIM;
    float acc[16];
    #pragma unroll
    for (int j = 0; j < 16; ++j) acc[j] = 0.f;
    #pragma unroll
    for (int it = 0; it < 8; ++it) {
        const int s1 = rg + it * 32;
        const uint4 vv = *(const uint4*)(vbase + (size_t)s1 * HEAD_DIM + d16);
        const float pp = pr[s1];
        f2v t;
        t = dec_lo(vv.x); acc[0]  = fmaf(pp, t.x, acc[0]);  acc[1]  = fmaf(pp, t.y, acc[1]);
        t = dec_hi(vv.x); acc[2]  = fmaf(pp, t.x, acc[2]);  acc[3]  = fmaf(pp, t.y, acc[3]);
        t = dec_lo(vv.y); acc[4]  = fmaf(pp, t.x, acc[4]);  acc[5]  = fmaf(pp, t.y, acc[5]);
        t = dec_hi(vv.y); acc[6]  = fmaf(pp, t.x, acc[6]);  acc[7]  = fmaf(pp, t.y, acc[7]);
        t = dec_lo(vv.z); acc[8]  = fmaf(pp, t.x, acc[8]);  acc[9]  = fmaf(pp, t.y, acc[9]);
        t = dec_hi(vv.z); acc[10] = fmaf(pp, t.x, acc[10]); acc[11] = fmaf(pp, t.y, acc[11]);
        t = dec_lo(vv.w); acc[12] = fmaf(pp, t.x, acc[12]); acc[13] = fmaf(pp, t.y, acc[13]);
        t = dec_hi(vv.w); acc[14] = fmaf(pp, t.x, acc[14]); acc[15] = fmaf(pp, t.y, acc[15]);
    }
    #pragma unroll
    for (int j = 0; j < 16; j += 4)
        *(float4*)&vred[rg][d16 + j] = make_float4(acc[j], acc[j+1], acc[j+2], acc[j+3]);
    __syncthreads();

    float* __restrict__ ph = part_out + ((size_t)h * SPLITS + sp) * PART_STRIDE;
    if (tid < HEAD_DIM) {
        float a = 0.f;
        #pragma unroll
        for (int g = 0; g < 32; ++g) a += vred[g][tid];
        ph[2 + tid] = a;
    }
    if (tid == 0) { ph[0] = M; ph[1] = L; }
}

// ---- final combine -> x out ----
__global__ __launch_bounds__(128)
void attn_combine(const float* __restrict__ part, float* __restrict__ xout)
{
    const int h = blockIdx.x;
    const int d = threadIdx.x;
    const float* __restrict__ ph = part + (size_t)h * SPLITS * PART_STRIDE;

    float G = -3.0e38f;
    #pragma unroll
    for (int i = 0; i < SPLITS; ++i) G = fmaxf(G, ph[i * PART_STRIDE]);

    float L = 0.f, acc = 0.f;
    #pragma unroll
    for (int i = 0; i < SPLITS; ++i) {
        const float w = __expf(ph[i * PART_STRIDE] - G);
        L   = fmaf(ph[i * PART_STRIDE + 1], w, L);
        acc = fmaf(ph[i * PART_STRIDE + 2 + d], w, acc);
    }
    xout[h * HEAD_DIM + d] = acc / L;
}

extern "C" void kernel_launch(void* const* d_in, const int* in_sizes, int n_in,
                              void* d_out, int out_size, void* d_ws, size_t ws_size,
                              hipStream_t stream)
{
    const float* x = (const float*)d_in[0];
    const float* k = (const float*)d_in[1];
    const float* v = (const float*)d_in[2];
    float* out = (float*)d_out;

    const size_t kvN = (size_t)NHEADS * SLEN * HEAD_DIM;       // 33,554,432
    const size_t partElems = (size_t)NHEADS * SPLITS * PART_STRIDE;

    float* part0 = (float*)d_ws;
    float* part1 = part0 + partElems;

    const size_t needWs = 2 * partElems * sizeof(float) + 2 * kvN * sizeof(uchar);
    uchar* kbt;
    uchar* vb;
    const bool ws_path = (ws_size >= needWs + 256);
    if (ws_path) kbt = (uchar*)(part0 + 2 * partElems);
    else         kbt = (uchar*)out;   // temp scratch in out K/V region; copy_kv at end
    vb = kbt + kvN;

    if (ws_path) {
        convert_kT<true><<<NHEADS * 128, 256, 0, stream>>>(k, kbt, out);
        convert_v<true><<<2048, 256, 0, stream>>>(
            (const float4*)v, (uint4*)vb, (float4*)(out + kvN), kvN / 16);
    } else {
        convert_kT<false><<<NHEADS * 128, 256, 0, stream>>>(k, kbt, nullptr);
        convert_v<false><<<2048, 256, 0, stream>>>(
            (const float4*)v, (uint4*)vb, nullptr, kvN / 16);
    }

    for (int layer = 0; layer < NLAYERS; ++layer) {
        float* pout = (layer & 1) ? part1 : part0;
        const float* pin = (layer == 0) ? nullptr : ((layer & 1) ? part0 : part1);
        attn_layer<<<NHEADS * SPLITS, 256, 0, stream>>>(
            (layer == 0) ? x : nullptr, pin, kbt, vb, pout);
    }
    attn_combine<<<NHEADS, 128, 0, stream>>>(part1, out + 2 * kvN);  // layer 31 -> part1

    if (!ws_path) {
        copy_kv<<<2048, 256, 0, stream>>>((const float4*)k, (const float4*)v,
                                          (float4*)out, kvN / 4);
    }
}

// Round 6
// 445.747 us; speedup vs baseline: 7.0954x; 1.4336x over previous
//
#include <hip/hip_runtime.h>
#include <math.h>

#define HEAD_DIM 128
#define NHEADS   32
#define SLEN     8192
#define SPLITS   32
#define CHUNK    (SLEN / SPLITS)   /* 256 */
#define NLAYERS  32
#define PART_STRIDE (HEAD_DIM + 2) /* m, l, acc[128] */
#define KROW     (SLEN / 2)        /* K^T fp4 row bytes = 4096 */
#define VROW     (HEAD_DIM / 2)    /* V fp4 row bytes = 64 */

typedef unsigned int   uint;
typedef unsigned short ushort;
typedef unsigned char  uchar;
typedef __attribute__((ext_vector_type(2))) float f2v;

// ---- fp4 e2m1 hardware converters (gfx950), scale = 1.0 ----
__device__ __forceinline__ f2v d4_0(uint w) { return __builtin_amdgcn_cvt_scalef32_pk_f32_fp4(w, 1.0f, 0); }
__device__ __forceinline__ f2v d4_1(uint w) { return __builtin_amdgcn_cvt_scalef32_pk_f32_fp4(w, 1.0f, 1); }
__device__ __forceinline__ f2v d4_2(uint w) { return __builtin_amdgcn_cvt_scalef32_pk_f32_fp4(w, 1.0f, 2); }
__device__ __forceinline__ f2v d4_3(uint w) { return __builtin_amdgcn_cvt_scalef32_pk_f32_fp4(w, 1.0f, 3); }

__device__ __forceinline__ uint pk8_fp4(float a0, float a1, float a2, float a3,
                                        float a4, float a5, float a6, float a7) {
    uint r = 0;
    r = __builtin_amdgcn_cvt_scalef32_pk_fp4_f32(r, a0, a1, 1.0f, 0);
    r = __builtin_amdgcn_cvt_scalef32_pk_fp4_f32(r, a2, a3, 1.0f, 1);
    r = __builtin_amdgcn_cvt_scalef32_pk_fp4_f32(r, a4, a5, 1.0f, 2);
    r = __builtin_amdgcn_cvt_scalef32_pk_fp4_f32(r, a6, a7, 1.0f, 3);
    return r;
}

// ---- K: fp32 [h][s][d] -> fp4 TRANSPOSED [h][d][s] (+ optional fp32 copy-out) ----
template<bool WRITE_OUT>
__global__ __launch_bounds__(256)
void convert_kT(const float* __restrict__ k, uchar* __restrict__ kbt,
                float* __restrict__ kout)
{
    const int h   = blockIdx.x >> 7;      // 128 s-tiles of 64 per head
    const int st  = blockIdx.x & 127;
    const int tid = threadIdx.x;

    __shared__ float tile[HEAD_DIM][65];  // [d][s_local], padded

    const int   srow0 = tid >> 5;         // 0..7
    const int   c4    = (tid & 31) * 4;   // 0..124
    const size_t kbase = ((size_t)h * SLEN + (size_t)st * 64) * HEAD_DIM;

    #pragma unroll
    for (int it = 0; it < 8; ++it) {
        const int s = srow0 + it * 8;
        const float4 v = *(const float4*)(k + kbase + (size_t)s * HEAD_DIM + c4);
        if (WRITE_OUT) *(float4*)(kout + kbase + (size_t)s * HEAD_DIM + c4) = v;
        tile[c4 + 0][s] = v.x; tile[c4 + 1][s] = v.y;
        tile[c4 + 2][s] = v.z; tile[c4 + 3][s] = v.w;
    }
    __syncthreads();

    const int d0  = tid >> 3;             // 0..31
    const int sl8 = (tid & 7) * 8;        // element offset 0..56
    #pragma unroll
    for (int it = 0; it < 4; ++it) {
        const int d = d0 + it * 32;
        const uint u = pk8_fp4(tile[d][sl8 + 0], tile[d][sl8 + 1],
                               tile[d][sl8 + 2], tile[d][sl8 + 3],
                               tile[d][sl8 + 4], tile[d][sl8 + 5],
                               tile[d][sl8 + 6], tile[d][sl8 + 7]);
        *(uint*)(kbt + ((size_t)h * HEAD_DIM + d) * KROW + st * 32 + (tid & 7) * 4) = u;
    }
}

// ---- V: fp32 -> fp4 row-major (+ optional fp32 copy-out) ----
template<bool WRITE_OUT>
__global__ void convert_v(const float4* __restrict__ v, uint2* __restrict__ vb,
                          float4* __restrict__ vout, size_t n16)
{
    size_t i = (size_t)blockIdx.x * blockDim.x + threadIdx.x;
    const size_t stride = (size_t)gridDim.x * blockDim.x;
    for (size_t j = i; j < n16; j += stride) {
        const float4 b0 = v[4 * j], b1 = v[4 * j + 1], b2 = v[4 * j + 2], b3 = v[4 * j + 3];
        if (WRITE_OUT) {
            vout[4 * j] = b0; vout[4 * j + 1] = b1;
            vout[4 * j + 2] = b2; vout[4 * j + 3] = b3;
        }
        uint2 p;
        p.x = pk8_fp4(b0.x, b0.y, b0.z, b0.w, b1.x, b1.y, b1.z, b1.w);
        p.y = pk8_fp4(b2.x, b2.y, b2.z, b2.w, b3.x, b3.y, b3.z, b3.w);
        vb[j] = p;
    }
}

// ---- fallback copy ----
__global__ void copy_kv(const float4* __restrict__ k, const float4* __restrict__ v,
                        float4* __restrict__ out, size_t n4)
{
    size_t i = (size_t)blockIdx.x * blockDim.x + threadIdx.x;
    const size_t stride = (size_t)gridDim.x * blockDim.x;
    for (size_t j = i; j < n4; j += stride) {
        out[j]      = k[j];
        out[n4 + j] = v[j];
    }
}

// ---- fused layer: combine(prev partials) -> x, then split attention ----
__global__ __launch_bounds__(256)
void attn_layer(const float* __restrict__ x0,
                const float* __restrict__ part_in,
                const uchar* __restrict__ kbt,   // fp4 K^T [32,128,8192]
                const uchar* __restrict__ vb,    // fp4 V   [32,8192,128]
                float* __restrict__ part_out)
{
    const int h    = blockIdx.x >> 5;
    const int sp   = blockIdx.x & 31;
    const int tid  = threadIdx.x;   // 0..255
    const int lane = tid & 63;
    const int w    = tid >> 6;

    __shared__ float xs[HEAD_DIM];
    __shared__ float scp[4][CHUNK];        // 4 KB
    __shared__ float pr[CHUNK];
    __shared__ float mred[4], lred[4];
    __shared__ float vred[32][HEAD_DIM];   // 16 KB

    // ---- prologue: produce x for this head ----
    if (part_in) {
        if (tid < HEAD_DIM) {
            const float* __restrict__ ph = part_in + (size_t)h * SPLITS * PART_STRIDE;
            float G = -3.0e38f;
            #pragma unroll
            for (int i = 0; i < SPLITS; ++i) G = fmaxf(G, ph[i * PART_STRIDE]);
            float L = 0.f, a = 0.f;
            #pragma unroll
            for (int i = 0; i < SPLITS; ++i) {
                const float wv = __expf(ph[i * PART_STRIDE] - G);
                L = fmaf(ph[i * PART_STRIDE + 1], wv, L);
                a = fmaf(ph[i * PART_STRIDE + 2 + tid], wv, a);
            }
            xs[tid] = a / L;
        }
    } else {
        if (tid < HEAD_DIM) xs[tid] = x0[h * HEAD_DIM + tid];
    }
    __syncthreads();

    // ---- QK from fp4 K^T: lane owns 16 consecutive s (uint2 = 8B) ----
    const int sgrp = lane & 15;
    const int s0   = sgrp * 16;
    const int dgrp = lane >> 4;           // 0..3
    const uchar* __restrict__ kh = kbt + (size_t)h * HEAD_DIM * KROW + (size_t)sp * (CHUNK / 2);
    float a16[16];
    #pragma unroll
    for (int j = 0; j < 16; ++j) a16[j] = 0.f;
    #pragma unroll
    for (int it = 0; it < 8; ++it) {
        const int d = it * 16 + (w << 2) + dgrp;
        const uint2 kk = *(const uint2*)(kh + (size_t)d * KROW + sgrp * 8);
        const float xd = xs[d];
        f2v t;
        t = d4_0(kk.x); a16[0]  = fmaf(t.x, xd, a16[0]);  a16[1]  = fmaf(t.y, xd, a16[1]);
        t = d4_1(kk.x); a16[2]  = fmaf(t.x, xd, a16[2]);  a16[3]  = fmaf(t.y, xd, a16[3]);
        t = d4_2(kk.x); a16[4]  = fmaf(t.x, xd, a16[4]);  a16[5]  = fmaf(t.y, xd, a16[5]);
        t = d4_3(kk.x); a16[6]  = fmaf(t.x, xd, a16[6]);  a16[7]  = fmaf(t.y, xd, a16[7]);
        t = d4_0(kk.y); a16[8]  = fmaf(t.x, xd, a16[8]);  a16[9]  = fmaf(t.y, xd, a16[9]);
        t = d4_1(kk.y); a16[10] = fmaf(t.x, xd, a16[10]); a16[11] = fmaf(t.y, xd, a16[11]);
        t = d4_2(kk.y); a16[12] = fmaf(t.x, xd, a16[12]); a16[13] = fmaf(t.y, xd, a16[13]);
        t = d4_3(kk.y); a16[14] = fmaf(t.x, xd, a16[14]); a16[15] = fmaf(t.y, xd, a16[15]);
    }
    #pragma unroll
    for (int j = 0; j < 16; ++j) {
        a16[j] += __shfl_xor(a16[j], 16);
        a16[j] += __shfl_xor(a16[j], 32);
    }
    if (lane < 16) {
        #pragma unroll
        for (int j = 0; j < 16; j += 4)
            *(float4*)&scp[w][s0 + j] = make_float4(a16[j], a16[j+1], a16[j+2], a16[j+3]);
    }
    __syncthreads();

    const float s = (scp[0][tid] + scp[1][tid] + scp[2][tid] + scp[3][tid])
                    * 0.088388347648318447f;  // 1/sqrt(128)

    // ---- block max ----
    float m = s;
    #pragma unroll
    for (int off = 1; off < 64; off <<= 1)
        m = fmaxf(m, __shfl_xor(m, off));
    if (lane == 0) mred[w] = m;
    __syncthreads();
    const float M = fmaxf(fmaxf(mred[0], mred[1]), fmaxf(mred[2], mred[3]));

    // ---- exp + block sum; probs to LDS ----
    const float p = __expf(s - M);
    pr[tid] = p;
    float l = p;
    #pragma unroll
    for (int off = 1; off < 64; off <<= 1)
        l += __shfl_xor(l, off);
    if (lane == 0) lred[w] = l;
    __syncthreads();
    const float L = lred[0] + lred[1] + lred[2] + lred[3];

    // ---- PV: thread owns 16 dims (uint2 fp4), 32 row-groups ----
    const int rg  = tid >> 3;          // 0..31
    const int dg  = tid & 7;           // d16 = dg*16
    const int d16 = dg * 16;
    const uchar* __restrict__ vbase = vb + ((size_t)h * SLEN + (size_t)sp * CHUNK) * VROW;
    float acc[16];
    #pragma unroll
    for (int j = 0; j < 16; ++j) acc[j] = 0.f;
    #pragma unroll
    for (int it = 0; it < 8; ++it) {
        const int s1 = rg + it * 32;
        const uint2 vv = *(const uint2*)(vbase + (size_t)s1 * VROW + dg * 8);
        const float pp = pr[s1];
        f2v t;
        t = d4_0(vv.x); acc[0]  = fmaf(pp, t.x, acc[0]);  acc[1]  = fmaf(pp, t.y, acc[1]);
        t = d4_1(vv.x); acc[2]  = fmaf(pp, t.x, acc[2]);  acc[3]  = fmaf(pp, t.y, acc[3]);
        t = d4_2(vv.x); acc[4]  = fmaf(pp, t.x, acc[4]);  acc[5]  = fmaf(pp, t.y, acc[5]);
        t = d4_3(vv.x); acc[6]  = fmaf(pp, t.x, acc[6]);  acc[7]  = fmaf(pp, t.y, acc[7]);
        t = d4_0(vv.y); acc[8]  = fmaf(pp, t.x, acc[8]);  acc[9]  = fmaf(pp, t.y, acc[9]);
        t = d4_1(vv.y); acc[10] = fmaf(pp, t.x, acc[10]); acc[11] = fmaf(pp, t.y, acc[11]);
        t = d4_2(vv.y); acc[12] = fmaf(pp, t.x, acc[12]); acc[13] = fmaf(pp, t.y, acc[13]);
        t = d4_3(vv.y); acc[14] = fmaf(pp, t.x, acc[14]); acc[15] = fmaf(pp, t.y, acc[15]);
    }
    #pragma unroll
    for (int j = 0; j < 16; j += 4)
        *(float4*)&vred[rg][d16 + j] = make_float4(acc[j], acc[j+1], acc[j+2], acc[j+3]);
    __syncthreads();

    float* __restrict__ ph = part_out + ((size_t)h * SPLITS + sp) * PART_STRIDE;
    if (tid < HEAD_DIM) {
        float a = 0.f;
        #pragma unroll
        for (int g = 0; g < 32; ++g) a += vred[g][tid];
        ph[2 + tid] = a;
    }
    if (tid == 0) { ph[0] = M; ph[1] = L; }
}

// ---- final combine -> x out ----
__global__ __launch_bounds__(128)
void attn_combine(const float* __restrict__ part, float* __restrict__ xout)
{
    const int h = blockIdx.x;
    const int d = threadIdx.x;
    const float* __restrict__ ph = part + (size_t)h * SPLITS * PART_STRIDE;

    float G = -3.0e38f;
    #pragma unroll
    for (int i = 0; i < SPLITS; ++i) G = fmaxf(G, ph[i * PART_STRIDE]);

    float L = 0.f, acc = 0.f;
    #pragma unroll
    for (int i = 0; i < SPLITS; ++i) {
        const float w = __expf(ph[i * PART_STRIDE] - G);
        L   = fmaf(ph[i * PART_STRIDE + 1], w, L);
        acc = fmaf(ph[i * PART_STRIDE + 2 + d], w, acc);
    }
    xout[h * HEAD_DIM + d] = acc / L;
}

extern "C" void kernel_launch(void* const* d_in, const int* in_sizes, int n_in,
                              void* d_out, int out_size, void* d_ws, size_t ws_size,
                              hipStream_t stream)
{
    const float* x = (const float*)d_in[0];
    const float* k = (const float*)d_in[1];
    const float* v = (const float*)d_in[2];
    float* out = (float*)d_out;

    const size_t kvN = (size_t)NHEADS * SLEN * HEAD_DIM;       // 33,554,432
    const size_t partElems = (size_t)NHEADS * SPLITS * PART_STRIDE;

    float* part0 = (float*)d_ws;
    float* part1 = part0 + partElems;

    const size_t needWs = 2 * partElems * sizeof(float) + kvN;  // fp4: kvN/2 *2 tensors
    uchar* kbt;
    uchar* vb;
    const bool ws_path = (ws_size >= needWs + 256);
    if (ws_path) kbt = (uchar*)(part0 + 2 * partElems);
    else         kbt = (uchar*)out;   // temp scratch in out K/V region; copy_kv at end
    vb = kbt + kvN / 2;

    if (ws_path) {
        convert_kT<true><<<NHEADS * 128, 256, 0, stream>>>(k, kbt, out);
        convert_v<true><<<2048, 256, 0, stream>>>(
            (const float4*)v, (uint2*)vb, (float4*)(out + kvN), kvN / 16);
    } else {
        convert_kT<false><<<NHEADS * 128, 256, 0, stream>>>(k, kbt, nullptr);
        convert_v<false><<<2048, 256, 0, stream>>>(
            (const float4*)v, (uint2*)vb, nullptr, kvN / 16);
    }

    for (int layer = 0; layer < NLAYERS; ++layer) {
        float* pout = (layer & 1) ? part1 : part0;
        const float* pin = (layer == 0) ? nullptr : ((layer & 1) ? part0 : part1);
        attn_layer<<<NHEADS * SPLITS, 256, 0, stream>>>(
            (layer == 0) ? x : nullptr, pin, kbt, vb, pout);
    }
    attn_combine<<<NHEADS, 128, 0, stream>>>(part1, out + 2 * kvN);  // layer 31 -> part1

    if (!ws_path) {
        copy_kv<<<2048, 256, 0, stream>>>((const float4*)k, (const float4*)v,
                                          (float4*)out, kvN / 4);
    }
}